// Round 6
// baseline (6153.893 us; speedup 1.0000x reference)
//
#include <hip/hip_runtime.h>

// ---------------------------------------------------------------------------
// 2-layer tanh RNN, B=64, T=512, I=256, H=512.  Round 11: R6 skeleton with
// serial events removed from each recurrence chain.
//   R10 post-mortem: VGPR_Count=64 -> weights remat'd from global in-loop
//   (weight array alone is 64 VGPR); L1 had 3 serialized compute phases
//   behind 4 barriers/step.  R6's per-lane direct loads (no staging barrier)
//   remain the fastest measured pattern.
// This round:
//   - L0: own half in LDS dbuf (epilogue-written, no LLC round-trip);
//     own-half MFMAs prehoisted before the peer-flag wait; peer half via
//     per-lane DIRECT loads into MFMA A-fragments (first-touch, flag-gated);
//     epilogue tanh -> per-wave LDS transpose -> coalesced 8B sc1 stores ->
//     vmcnt(0) -> ONE barrier -> flag.
//   - L1: concurrent pair (part0 hh | part1 ih) with per-lane direct loads,
//     one red-sync, part0 epilogue, drain-sync, flag.  2 barriers/step.
//   - weights pinned in VGPRs via keep-alive asm; both branches <=~126 VGPR.
//   - every flag on its own 128B line.
//   - xw = x@Wih0+biases precomputed into d_out (proven aliasing: L0 reads
//     xw[b][t] strictly before L1 overwrites out1[b][t]).
// ---------------------------------------------------------------------------

#define kB 64
#define kT 512
#define kI 256
#define kH 512
#define kBH (kB * kH)   // 32768

typedef _Float16 half8 __attribute__((ext_vector_type(8)));
typedef float floatx4 __attribute__((ext_vector_type(4)));
typedef unsigned u32x4 __attribute__((ext_vector_type(4)));
typedef unsigned u32x2 __attribute__((ext_vector_type(2)));

#define MFMA(a, b, c) __builtin_amdgcn_mfma_f32_16x16x32_f16(a, b, c, 0, 0, 0)

// ws layout (bytes)
constexpr size_t W16_B   = 0;                      // wih0 fp16, 256 KB
constexpr size_t WH0_B   = 256u * 1024;            // whh0 fp16, 512 KB
constexpr size_t WI1_B   = WH0_B + 512u * 1024;    // wih1 fp16, 512 KB
constexpr size_t WH1_B   = WI1_B + 512u * 1024;    // whh1 fp16, 512 KB
constexpr size_t OUT0M_B = 2u * 1024 * 1024;                      // [T+1][B][H] fp16
constexpr size_t H1M_B   = OUT0M_B + (size_t)(kT + 1) * kBH * 2;  // [T+1][B][H] fp16
constexpr size_t CNT_B   = H1M_B + (size_t)(kT + 1) * kBH * 2;    // flags (1024 ints)

__device__ inline void agent_store8(void* p, u32x2 v) {
    asm volatile("global_store_dwordx2 %0, %1, off sc1" :: "v"(p), "v"(v) : "memory");
}
__device__ inline int aload(const int* p) {
    return __hip_atomic_load(p, __ATOMIC_RELAXED, __HIP_MEMORY_SCOPE_AGENT);
}
// flags live at f[i*32] (128B apart)
__device__ inline void wait_slot(const int* p, int target) {
    int g = 0;
    while (aload(p) < target) if (++g > 100000000) break;   // fail-wrong, not hang
    asm volatile("" ::: "memory");   // keep gated loads below the gate
}
__device__ inline void wait_pair(const int* f, int target) {
    const int* p = f + (threadIdx.x & 1) * 32;
    int g = 0;
    for (;;) { int v = aload(p); if (__all(v >= target)) break; if (++g > 100000000) break; }
    asm volatile("" ::: "memory");
}
__device__ inline void wait_quad(const int* f, int own, int target) {
    const int idx = threadIdx.x & 3;
    const int* p = f + idx * 32;
    int g = 0;
    for (;;) {
        int v = (idx == own) ? target : aload(p);
        if (__all(v >= target)) break;
        if (++g > 100000000) break;
    }
    asm volatile("" ::: "memory");
}

__device__ inline float fast_tanh(float x) {
    float e = __expf(2.f * x);
    return 1.f - 2.f / (e + 1.f);   // exact +-1 saturation, no NaN
}

__device__ inline half8 cvt8(const float* p) {
    const float4* p4 = (const float4*)p;
    float4 a = p4[0], b = p4[1];
    half8 h;
    h[0] = (_Float16)a.x; h[1] = (_Float16)a.y; h[2] = (_Float16)a.z; h[3] = (_Float16)a.w;
    h[4] = (_Float16)b.x; h[5] = (_Float16)b.y; h[6] = (_Float16)b.z; h[7] = (_Float16)b.w;
    return h;
}

// ---------------------------------------------------------------------------
__global__ void setup_kernel(const float* __restrict__ h0,
                             const float* __restrict__ wih0, const float* __restrict__ whh0,
                             const float* __restrict__ wih1, const float* __restrict__ whh1,
                             _Float16* __restrict__ w16, _Float16* __restrict__ wh0_16,
                             _Float16* __restrict__ wi1_16, _Float16* __restrict__ wh1_16,
                             _Float16* __restrict__ out0m, _Float16* __restrict__ h1m,
                             int* __restrict__ cnt) {
    size_t tid = (size_t)blockIdx.x * blockDim.x + threadIdx.x;
    size_t stride = (size_t)gridDim.x * blockDim.x;
    for (size_t i = tid; i < (size_t)kH * kI; i += stride) w16[i] = (_Float16)wih0[i];
    for (size_t i = tid; i < (size_t)kH * kH; i += stride) {
        wh0_16[i] = (_Float16)whh0[i];
        wi1_16[i] = (_Float16)wih1[i];
        wh1_16[i] = (_Float16)whh1[i];
    }
    for (size_t i = tid; i < kBH; i += stride) {
        out0m[i] = (_Float16)h0[i];          // h(0) layer0 -> slab 0
        h1m[i]   = (_Float16)h0[kBH + i];    // h(0) layer1 -> slab 0
    }
    if (tid < 1024) cnt[tid] = 0;
}

// xw[b][t][c] = sum_i x[b,t,i]*Wih0[c,i] + bih0[c] + bhh0[c]   (fp32, into d_out)
__global__ __launch_bounds__(256) void xw_kernel(
    const float* __restrict__ x, const _Float16* __restrict__ w16,
    const float* __restrict__ bih, const float* __restrict__ bhh, float* xw) {
    const int mb = blockIdx.x >> 3, nb = blockIdx.x & 7;
    const int wave = threadIdx.x >> 6, lane = threadIdx.x & 63;
    const int r = lane & 15, q = lane >> 4;
    const int m0 = mb * 64 + wave * 16;
    half8 a[8];
#pragma unroll
    for (int ko = 0; ko < 8; ++ko)
        a[ko] = cvt8(x + (size_t)(m0 + r) * kI + ko * 32 + q * 8);
#pragma unroll
    for (int ct = 0; ct < 4; ++ct) {
        const int cc = nb * 64 + ct * 16 + r;
        const float bias = bih[cc] + bhh[cc];
        floatx4 acc = {bias, bias, bias, bias};
#pragma unroll
        for (int ko = 0; ko < 8; ++ko) {
            half8 b = *(const half8*)(w16 + (size_t)cc * kI + ko * 32 + q * 8);
            acc = MFMA(a[ko], b, acc);
        }
#pragma unroll
        for (int j = 0; j < 4; ++j)
            xw[(size_t)(m0 + q * 4 + j) * kH + cc] = acc[j];
    }
}

// ---------------------------------------------------------------------------
__global__ __launch_bounds__(1024, 4) void scan_kernel(
    const float* xw,                       // = d_out (fp32 [B][T][H]), layer0 reads
    _Float16* out0m, _Float16* h1m,
    float* out1,                           // = d_out, layer1 writes
    const _Float16* __restrict__ wh0_16,
    const _Float16* __restrict__ wi1_16, const _Float16* __restrict__ wh1_16,
    const float* __restrict__ bih1, const float* __restrict__ bhh1,
    int* cnt) {
    __shared__ __align__(16) char smem[24576];

    const int blk = blockIdx.x;
    const int tid = threadIdx.x;
    const int wave = tid >> 6, lane = tid & 63;
    const int r = lane & 15, q = lane >> 4;
    const int swzr = (r & 7) << 4;
    const int rr = lane >> 2, cg = lane & 3;         // epilogue transpose roles

    if (blk < 8) {
        // ================= layer 0: 4 groups x 2 col-halves =================
        const int g = blk >> 1, hf = blk & 1;
        const int b0 = g * 16;
        const int cb = hf * 256 + wave * 16;         // absolute col base (16/wave)
        half8 wfh[16];                               // full-K weights, 64 VGPR
#pragma unroll
        for (int ks = 0; ks < 16; ++ks) {
            wfh[ks] = *(const half8*)(wh0_16 + (size_t)(cb + r) * kH + ks * 32 + q * 8);
            u32x4 tmp = __builtin_bit_cast(u32x4, wfh[ks]);
            asm volatile("" : "+v"(tmp));            // pin in VGPRs (defeat remat)
            wfh[ks] = __builtin_bit_cast(half8, tmp);
        }
        char* ownb = smem;                           // [2][16][512B] own half dbuf
        char* ts = smem + 16384 + wave * 512;        // per-wave [16][16] fp16
        int* myf = cnt + (g * 2 + hf) * 32;
        const int* pef = cnt + (g * 2 + (hf ^ 1)) * 32;

        // prestage own half of h(0) into parity-0 buffer
        if (tid < 512) {
            const int row = tid >> 5, u = tid & 31;
            u32x4 v = *(const u32x4*)(out0m + (size_t)(b0 + row) * kH + hf * 256 + u * 8);
            *(u32x4*)(ownb + row * 512 + ((u * 16) ^ ((row & 7) << 4))) = v;
        }
        __syncthreads();

        const _Float16* pb = out0m + (size_t)(b0 + r) * kH + (hf ^ 1) * 256 + q * 8;
        _Float16* st = out0m + (size_t)kBH + (size_t)(b0 + rr) * kH + cb + cg * 4;
        const float* xwp = xw + (size_t)(b0 + q * 4) * kT * kH + cb + r;

        for (int t = 0; t < kT; ++t) {
            char* bufR = ownb + (t & 1) * 8192;
            char* bufW = ownb + ((t + 1) & 1) * 8192;
            // flag-independent work FIRST: xw prefetch + own-half MFMAs
            float xv[4];
#pragma unroll
            for (int j = 0; j < 4; ++j)
                xv[j] = xwp[(size_t)j * kT * kH + (size_t)t * kH];
            floatx4 acc = {0.f, 0.f, 0.f, 0.f};
#pragma unroll
            for (int i = 0; i < 8; ++i) {
                half8 la = *(const half8*)(bufR + r * 512 + ((i * 64 + q * 16) ^ swzr));
                acc = MFMA(la, wfh[hf * 8 + i], acc);
            }
            // gate, then per-lane DIRECT peer loads into MFMA fragments
            if (t > 0) wait_slot(pef, t);
            u32x4 ph[8];
#pragma unroll
            for (int i = 0; i < 8; ++i) ph[i] = *(const u32x4*)(pb + i * 32);
#pragma unroll
            for (int i = 0; i < 8; ++i)
                acc = MFMA(__builtin_bit_cast(half8, ph[i]), wfh[(hf ^ 1) * 8 + i], acc);
            // epilogue: tanh -> per-wave transpose -> coalesced 8B sc1 store
#pragma unroll
            for (int j = 0; j < 4; ++j) {
                float v = fast_tanh(acc[j] + xv[j]);
                *(_Float16*)(ts + (q * 4 + j) * 32 + r * 2) = (_Float16)v;
            }
            asm volatile("s_waitcnt lgkmcnt(0)" ::: "memory");
            u32x2 tv = *(const u32x2*)(ts + rr * 32 + cg * 8);
            agent_store8(st, tv);
            *(u32x2*)(bufW + rr * 512 + ((wave * 32 + cg * 8) ^ ((rr & 7) << 4))) = tv;
            // publish: drain -> ONE barrier -> flag
            asm volatile("" ::: "memory");
            __builtin_amdgcn_s_waitcnt(0x0F70);      // vmcnt(0)
            __syncthreads();
            if (tid == 0)
                __hip_atomic_store(myf, t + 1, __ATOMIC_RELAXED, __HIP_MEMORY_SCOPE_AGENT);
            pb += kBH; st += kBH;
        }
    } else {
        // ================= layer 1: 4 groups x 4 col-quarters =================
        const int b2 = blk - 8;
        const int g = b2 >> 2, qb = b2 & 3;
        const int b0 = g * 16;
        const int p = wave >> 1, part = wave & 1;    // pair: part0=hh, part1=ih
        const int c0 = qb * 128 + p * 16;
        half8 wf[16];                                // one matrix full-K, 64 VGPR
        const _Float16* wsrc = part ? wi1_16 : wh1_16;
#pragma unroll
        for (int ks = 0; ks < 16; ++ks) {
            wf[ks] = *(const half8*)(wsrc + (size_t)(c0 + r) * kH + ks * 32 + q * 8);
            u32x4 tmp = __builtin_bit_cast(u32x4, wf[ks]);
            asm volatile("" : "+v"(tmp));            // pin in VGPRs
            wf[ks] = __builtin_bit_cast(half8, tmp);
        }
        const float bias = bih1[c0 + r] + bhh1[c0 + r];
        char* red = smem + p * 1024;                 // per-pair 1KB reduce buf
        char* ts  = smem + 8192 + p * 512;           // per-pair transpose (part0)
        int* myf = cnt + (8 + g * 4 + qb) * 32;
        const int* qf = cnt + (8 + g * 4) * 32;      // own-layer quarter flags
        const int* lf = cnt + g * 2 * 32;            // layer0 half flags

        const _Float16* hb = h1m + (size_t)(b0 + r) * kH + q * 8;                 // slab t
        const _Float16* ob = out0m + (size_t)kBH + (size_t)(b0 + r) * kH + q * 8; // slab t+1
        _Float16* hst = h1m + (size_t)kBH + (size_t)(b0 + rr) * kH + c0 + cg * 4;
        float* o1 = out1 + (size_t)(b0 + q * 4) * kT * kH + c0 + r;

        for (int t = 0; t < kT; ++t) {
            floatx4 acc = {0.f, 0.f, 0.f, 0.f};
            if (part == 0) {
                // hh path: gate on own-layer peers, direct h1(t) loads
                if (t > 0) wait_quad(qf, qb, t);
                u32x4 fr[8];
#pragma unroll
                for (int i = 0; i < 8; ++i) fr[i] = *(const u32x4*)(hb + i * 32);
#pragma unroll
                for (int i = 0; i < 8; ++i)
                    acc = MFMA(__builtin_bit_cast(half8, fr[i]), wf[i], acc);
#pragma unroll
                for (int i = 0; i < 8; ++i) fr[i] = *(const u32x4*)(hb + 256 + i * 32);
#pragma unroll
                for (int i = 0; i < 8; ++i)
                    acc = MFMA(__builtin_bit_cast(half8, fr[i]), wf[8 + i], acc);
            } else {
                // ih path: gate on layer0, direct out0(t+1) loads
                wait_pair(lf, t + 1);
                u32x4 fr[8];
#pragma unroll
                for (int i = 0; i < 8; ++i) fr[i] = *(const u32x4*)(ob + i * 32);
#pragma unroll
                for (int i = 0; i < 8; ++i)
                    acc = MFMA(__builtin_bit_cast(half8, fr[i]), wf[i], acc);
#pragma unroll
                for (int i = 0; i < 8; ++i) fr[i] = *(const u32x4*)(ob + 256 + i * 32);
#pragma unroll
                for (int i = 0; i < 8; ++i)
                    acc = MFMA(__builtin_bit_cast(half8, fr[i]), wf[8 + i], acc);
                *(floatx4*)(red + lane * 16) = acc;
            }
            __syncthreads();                         // red ready
            float vj[4];
            if (part == 0) {
                floatx4 o = *(const floatx4*)(red + lane * 16);
#pragma unroll
                for (int j = 0; j < 4; ++j) {
                    vj[j] = fast_tanh(acc[j] + o[j] + bias);
                    *(_Float16*)(ts + (q * 4 + j) * 32 + r * 2) = (_Float16)vj[j];
                }
                asm volatile("s_waitcnt lgkmcnt(0)" ::: "memory");
                u32x2 tv = *(const u32x2*)(ts + rr * 32 + cg * 8);
                agent_store8(hst, tv);
            }
            asm volatile("" ::: "memory");
            __builtin_amdgcn_s_waitcnt(0x0F70);      // vmcnt(0)
            __syncthreads();                         // drained + red/ts reuse safe
            if (tid == 0)
                __hip_atomic_store(myf, t + 1, __ATOMIC_RELAXED, __HIP_MEMORY_SCOPE_AGENT);
            if (part == 0) {                         // out1 fp32 AFTER flag
#pragma unroll
                for (int j = 0; j < 4; ++j)
                    o1[(size_t)j * kT * kH + (size_t)t * kH] = vj[j];
            }
            hb += kBH; ob += kBH; hst += kBH;
        }
    }
}

__global__ void finalize_kernel(const _Float16* __restrict__ out0m,
                                const _Float16* __restrict__ h1m,
                                float* __restrict__ out) {
    int idx = blockIdx.x * blockDim.x + threadIdx.x;  // 0 .. 65535
    float* hn = out + (size_t)kB * kT * kH;
    if (idx < kBH) hn[idx] = (float)out0m[(size_t)kT * kBH + idx];
    else hn[idx] = (float)h1m[(size_t)kT * kBH + (idx - kBH)];
}

extern "C" void kernel_launch(void* const* d_in, const int* in_sizes, int n_in,
                              void* d_out, int out_size, void* d_ws, size_t ws_size,
                              hipStream_t stream) {
    const float* x    = (const float*)d_in[0];
    const float* h0in = (const float*)d_in[1];
    const float* wih0 = (const float*)d_in[2];
    const float* whh0 = (const float*)d_in[3];
    const float* bih0 = (const float*)d_in[4];
    const float* bhh0 = (const float*)d_in[5];
    const float* wih1 = (const float*)d_in[6];
    const float* whh1 = (const float*)d_in[7];
    const float* bih1 = (const float*)d_in[8];
    const float* bhh1 = (const float*)d_in[9];
    float* out = (float*)d_out;
    char* ws = (char*)d_ws;

    _Float16* w16    = (_Float16*)(ws + W16_B);
    _Float16* wh0_16 = (_Float16*)(ws + WH0_B);
    _Float16* wi1_16 = (_Float16*)(ws + WI1_B);
    _Float16* wh1_16 = (_Float16*)(ws + WH1_B);
    _Float16* out0m  = (_Float16*)(ws + OUT0M_B);
    _Float16* h1m    = (_Float16*)(ws + H1M_B);
    int* cnt         = (int*)(ws + CNT_B);

    setup_kernel<<<2048, 256, 0, stream>>>(h0in, wih0, whh0, wih1, whh1,
                                           w16, wh0_16, wi1_16, wh1_16, out0m, h1m, cnt);
    xw_kernel<<<4096, 256, 0, stream>>>(x, w16, bih0, bhh0, out);
    scan_kernel<<<24, 1024, 0, stream>>>(out, out0m, h1m, out,
                                         wh0_16, wi1_16, wh1_16, bih1, bhh1, cnt);
    finalize_kernel<<<256, 256, 0, stream>>>(out0m, h1m, out);
}

// Round 7
// 4642.081 us; speedup vs baseline: 1.3257x; 1.3257x over previous
//
#include <hip/hip_runtime.h>

// ---------------------------------------------------------------------------
// 2-layer tanh RNN, B=64, T=512, I=256, H=512.  Round 12: R6 skeleton +
// three audited fixes, constant-indexed weight arrays everywhere.
//   R11 post-mortem: wfh[hf*8+i] (runtime index) -> array demoted to
//   SCRATCH (VGPR_Count=52) -> MFMA operands from scratch on the chain.
//   R6 (best, 2046us) had constant indexing; its speed never depended on
//   register residency (VGPR=64 there) -- only on avoiding scratch.
// Fixes vs R6:
//   1. L0 own 256-col half lives in an LDS double buffer written by the
//      epilogue (removes one global store->load RT per step); only the
//      peer half crosses the LLC.
//   2. Peer half: per-lane DIRECT loads into MFMA A-fragments after the
//      flag (R6-L1's proven pattern) -- no staging barrier.  One barrier
//      per L0 step.
//   3. Publish: tanh -> per-wave LDS transpose -> coalesced 8B sc1 stores
//      (replaces 4 scattered 2B stores/thread) -> vmcnt(0) -> barrier ->
//      one relaxed agent flag store (R5 recipe).  Flags 128B apart.
//   L1 keeps R6's concurrent (hh | ih) wave-pair structure with direct
//   loads, one reduce barrier + one drain barrier per step.
//   xw = x@Wih0+biases precomputed into d_out (aliasing proven R9-R11:
//   L0 consumes xw[b][t] strictly before L1 overwrites out1[b][t]).
// ---------------------------------------------------------------------------

#define kB 64
#define kT 512
#define kI 256
#define kH 512
#define kBH (kB * kH)   // 32768

typedef _Float16 half8 __attribute__((ext_vector_type(8)));
typedef float floatx4 __attribute__((ext_vector_type(4)));
typedef unsigned u32x4 __attribute__((ext_vector_type(4)));
typedef unsigned u32x2 __attribute__((ext_vector_type(2)));

#define MFMA(a, b, c) __builtin_amdgcn_mfma_f32_16x16x32_f16(a, b, c, 0, 0, 0)

// ws layout (bytes)
constexpr size_t W16_B   = 0;                      // wih0 fp16, 256 KB
constexpr size_t WH0_B   = 256u * 1024;            // whh0 fp16, 512 KB
constexpr size_t WI1_B   = WH0_B + 512u * 1024;    // wih1 fp16, 512 KB
constexpr size_t WH1_B   = WI1_B + 512u * 1024;    // whh1 fp16, 512 KB
constexpr size_t OUT0M_B = 2u * 1024 * 1024;                      // [T+1][B][H] fp16
constexpr size_t H1M_B   = OUT0M_B + (size_t)(kT + 1) * kBH * 2;  // [T+1][B][H] fp16
constexpr size_t CNT_B   = H1M_B + (size_t)(kT + 1) * kBH * 2;    // flags (1024 ints)

__device__ inline void agent_store8(void* p, u32x2 v) {
    asm volatile("global_store_dwordx2 %0, %1, off sc1" :: "v"(p), "v"(v) : "memory");
}
__device__ inline int aload(const int* p) {
    return __hip_atomic_load(p, __ATOMIC_RELAXED, __HIP_MEMORY_SCOPE_AGENT);
}
// flags live 128B apart (index * 32 ints)
__device__ inline void wait_slot(const int* p, int target) {
    int g = 0;
    while (aload(p) < target) if (++g > 100000000) break;   // fail-wrong, not hang
    asm volatile("" ::: "memory");   // keep gated loads below the gate
}
__device__ inline void wait_pair(const int* f, int target) {
    const int* p = f + (threadIdx.x & 1) * 32;
    int g = 0;
    for (;;) { int v = aload(p); if (__all(v >= target)) break; if (++g > 100000000) break; }
    asm volatile("" ::: "memory");
}
__device__ inline void wait_quad(const int* f, int own, int target) {
    const int idx = threadIdx.x & 3;
    const int* p = f + idx * 32;
    int g = 0;
    for (;;) {
        int v = (idx == own) ? target : aload(p);
        if (__all(v >= target)) break;
        if (++g > 100000000) break;
    }
    asm volatile("" ::: "memory");
}

__device__ inline float fast_tanh(float x) {
    float e = __expf(2.f * x);
    return 1.f - 2.f / (e + 1.f);
}

__device__ inline half8 cvt8(const float* p) {
    const float4* p4 = (const float4*)p;
    float4 a = p4[0], b = p4[1];
    half8 h;
    h[0] = (_Float16)a.x; h[1] = (_Float16)a.y; h[2] = (_Float16)a.z; h[3] = (_Float16)a.w;
    h[4] = (_Float16)b.x; h[5] = (_Float16)b.y; h[6] = (_Float16)b.z; h[7] = (_Float16)b.w;
    return h;
}

// ---------------------------------------------------------------------------
__global__ void setup_kernel(const float* __restrict__ h0,
                             const float* __restrict__ wih0, const float* __restrict__ whh0,
                             const float* __restrict__ wih1, const float* __restrict__ whh1,
                             _Float16* __restrict__ w16, _Float16* __restrict__ wh0_16,
                             _Float16* __restrict__ wi1_16, _Float16* __restrict__ wh1_16,
                             _Float16* __restrict__ out0m, _Float16* __restrict__ h1m,
                             int* __restrict__ cnt) {
    size_t tid = (size_t)blockIdx.x * blockDim.x + threadIdx.x;
    size_t stride = (size_t)gridDim.x * blockDim.x;
    for (size_t i = tid; i < (size_t)kH * kI; i += stride) w16[i] = (_Float16)wih0[i];
    for (size_t i = tid; i < (size_t)kH * kH; i += stride) {
        wh0_16[i] = (_Float16)whh0[i];
        wi1_16[i] = (_Float16)wih1[i];
        wh1_16[i] = (_Float16)whh1[i];
    }
    for (size_t i = tid; i < kBH; i += stride) {
        out0m[i] = (_Float16)h0[i];          // h(0) layer0 -> slab 0
        h1m[i]   = (_Float16)h0[kBH + i];    // h(0) layer1 -> slab 0
    }
    if (tid < 1024) cnt[tid] = 0;
}

// xw[b][t][c] = sum_i x[b,t,i]*Wih0[c,i] + bih0[c] + bhh0[c]   (fp32, into d_out)
__global__ __launch_bounds__(256) void xw_kernel(
    const float* __restrict__ x, const _Float16* __restrict__ w16,
    const float* __restrict__ bih, const float* __restrict__ bhh, float* xw) {
    const int mb = blockIdx.x >> 3, nb = blockIdx.x & 7;
    const int wave = threadIdx.x >> 6, lane = threadIdx.x & 63;
    const int r = lane & 15, q = lane >> 4;
    const int m0 = mb * 64 + wave * 16;
    half8 a[8];
#pragma unroll
    for (int ko = 0; ko < 8; ++ko)
        a[ko] = cvt8(x + (size_t)(m0 + r) * kI + ko * 32 + q * 8);
#pragma unroll
    for (int ct = 0; ct < 4; ++ct) {
        const int cc = nb * 64 + ct * 16 + r;
        const float bias = bih[cc] + bhh[cc];
        floatx4 acc = {bias, bias, bias, bias};
#pragma unroll
        for (int ko = 0; ko < 8; ++ko) {
            half8 b = *(const half8*)(w16 + (size_t)cc * kI + ko * 32 + q * 8);
            acc = MFMA(a[ko], b, acc);
        }
#pragma unroll
        for (int j = 0; j < 4; ++j)
            xw[(size_t)(m0 + q * 4 + j) * kH + cc] = acc[j];
    }
}

// ---------------------------------------------------------------------------
__global__ __launch_bounds__(1024) void scan_kernel(
    const float* xw,                       // = d_out (fp32 [B][T][H]), layer0 reads
    _Float16* out0m, _Float16* h1m,
    float* out1,                           // = d_out, layer1 writes
    const _Float16* __restrict__ wh0_16,
    const _Float16* __restrict__ wi1_16, const _Float16* __restrict__ wh1_16,
    const float* __restrict__ bih1, const float* __restrict__ bhh1,
    int* cnt) {
    __shared__ __align__(16) char smem[24576];

    const int blk = blockIdx.x;
    const int tid = threadIdx.x;
    const int wave = tid >> 6, lane = tid & 63;
    const int r = lane & 15, q = lane >> 4;
    const int swzr = (r & 7) << 4;
    const int rr = lane >> 2, cg = lane & 3;         // publish-transpose roles

    if (blk < 8) {
        // ============ layer 0: 4 groups x 2 halves, 16 waves x 16 cols ============
        const int g = blk >> 1, hf = blk & 1;
        const int b0 = g * 16;
        const int c0 = hf * 256 + wave * 16;         // absolute col base (16/wave)
        // full-K weights, split own/peer K-halves -- CONSTANT indexing only
        const _Float16* wrow = wh0_16 + (size_t)(c0 + r) * kH;
        half8 wfOwn[8], wfPeer[8];
#pragma unroll
        for (int i = 0; i < 8; ++i) {
            wfOwn[i]  = *(const half8*)(wrow + hf * 256 + i * 32 + q * 8);
            wfPeer[i] = *(const half8*)(wrow + (hf ^ 1) * 256 + i * 32 + q * 8);
        }
        char* ownb = smem;                           // [2][16 rows][512B] own-half dbuf
        char* ts = smem + 16384 + wave * 512;        // per-wave [16][16] fp16 transpose
        int* myf = cnt + (g * 2 + hf) * 32;
        const int* pef = cnt + (g * 2 + (hf ^ 1)) * 32;

        // prestage own half of h(0) into parity-0 buffer
        if (tid < 512) {
            const int row = tid >> 5, u = tid & 31;  // [16 rows][32 x 16B units]
            u32x4 v = *(const u32x4*)(out0m + (size_t)(b0 + row) * kH + hf * 256 + u * 8);
            *(u32x4*)(ownb + row * 512 + ((u * 16) ^ ((row & 7) << 4))) = v;
        }
        __syncthreads();

        const _Float16* pb = out0m + (size_t)(b0 + r) * kH + (hf ^ 1) * 256 + q * 8;
        _Float16* st = out0m + (size_t)kBH + (size_t)(b0 + rr) * kH + c0 + cg * 4;
        const float* xwp = xw + (size_t)(b0 + q * 4) * kT * kH + c0 + r;

        for (int t = 0; t < kT; ++t) {
            char* bufR = ownb + (t & 1) * 8192;
            char* bufW = ownb + ((t + 1) & 1) * 8192;
            // flag-independent first: xw prefetch + own-half MFMAs from LDS
            float xv[4];
#pragma unroll
            for (int j = 0; j < 4; ++j)
                xv[j] = xwp[(size_t)j * kT * kH + (size_t)t * kH];
            floatx4 acc = {0.f, 0.f, 0.f, 0.f};
#pragma unroll
            for (int i = 0; i < 8; ++i) {
                half8 la = *(const half8*)(bufR + r * 512 + ((i * 64 + q * 16) ^ swzr));
                acc = MFMA(la, wfOwn[i], acc);
            }
            // gate on peer flag, then DIRECT per-lane loads into fragments
            if (t > 0) wait_slot(pef, t);
            u32x4 ph[8];
#pragma unroll
            for (int i = 0; i < 8; ++i) ph[i] = *(const u32x4*)(pb + i * 32);
#pragma unroll
            for (int i = 0; i < 8; ++i)
                acc = MFMA(__builtin_bit_cast(half8, ph[i]), wfPeer[i], acc);
            // epilogue: tanh -> own-half LDS dbuf scatter + per-wave transpose
#pragma unroll
            for (int j = 0; j < 4; ++j) {
                float v = fast_tanh(acc[j] + xv[j]);
                const int row = q * 4 + j;
                *(_Float16*)(ts + row * 32 + r * 2) = (_Float16)v;
                *(_Float16*)(bufW + row * 512 +
                             (((wave * 16 + r) * 2) ^ ((row & 7) << 4))) = (_Float16)v;
            }
            asm volatile("s_waitcnt lgkmcnt(0)" ::: "memory");
            u32x2 tv = *(const u32x2*)(ts + rr * 32 + cg * 8);
            agent_store8(st, tv);                    // coalesced 8B agent store
            // publish: drain -> ONE barrier -> flag
            asm volatile("" ::: "memory");
            __builtin_amdgcn_s_waitcnt(0x0F70);      // vmcnt(0)
            __syncthreads();                         // also fences bufW for next step
            if (tid == 0)
                __hip_atomic_store(myf, t + 1, __ATOMIC_RELAXED, __HIP_MEMORY_SCOPE_AGENT);
            pb += kBH; st += kBH;
        }
    } else {
        // ============ layer 1: 4 groups x 4 quarters, 8 (hh|ih) pairs ============
        const int b2 = blk - 8;
        const int g = b2 >> 2, qb = b2 & 3;
        const int b0 = g * 16;
        const int p = wave >> 1, part = wave & 1;    // pair p, part0=hh part1=ih
        const int c0 = qb * 128 + p * 16;
        const _Float16* wsrc = part ? wi1_16 : wh1_16;
        half8 wf[16];                                // one matrix full-K, const-indexed
#pragma unroll
        for (int ks = 0; ks < 16; ++ks)
            wf[ks] = *(const half8*)(wsrc + (size_t)(c0 + r) * kH + ks * 32 + q * 8);
        const float bias = bih1[c0 + r] + bhh1[c0 + r];
        char* red = smem + p * 1024;                 // per-pair 1KB reduce buf
        char* ts  = smem + 8192 + p * 512;           // per-pair [16][16] fp16 (part0)
        int* myf = cnt + (8 + g * 4 + qb) * 32;
        const int* qf = cnt + (8 + g * 4) * 32;      // own-layer quarter flags
        const int* lf = cnt + g * 2 * 32;            // layer0 half flags

        const _Float16* hb = h1m + (size_t)(b0 + r) * kH + q * 8;                 // slab t
        const _Float16* ob = out0m + (size_t)kBH + (size_t)(b0 + r) * kH + q * 8; // slab t+1
        _Float16* hst = h1m + (size_t)kBH + (size_t)(b0 + rr) * kH + c0 + cg * 4;
        float* o1 = out1 + (size_t)(b0 + q * 4) * kT * kH + c0 + r;

        for (int t = 0; t < kT; ++t) {
            floatx4 acc = {0.f, 0.f, 0.f, 0.f};
            float vj[4];
            if (part == 0) {
                // hh path: gate on own-layer peers, direct h1(t) loads
                if (t > 0) wait_quad(qf, qb, t);
                u32x4 fr[8];
#pragma unroll
                for (int i = 0; i < 8; ++i) fr[i] = *(const u32x4*)(hb + i * 32);
#pragma unroll
                for (int i = 0; i < 8; ++i)
                    acc = MFMA(__builtin_bit_cast(half8, fr[i]), wf[i], acc);
#pragma unroll
                for (int i = 0; i < 8; ++i) fr[i] = *(const u32x4*)(hb + 256 + i * 32);
#pragma unroll
                for (int i = 0; i < 8; ++i)
                    acc = MFMA(__builtin_bit_cast(half8, fr[i]), wf[8 + i], acc);
            } else {
                // ih path: gate on layer0, direct out0(t+1) loads
                wait_pair(lf, t + 1);
                u32x4 fr[8];
#pragma unroll
                for (int i = 0; i < 8; ++i) fr[i] = *(const u32x4*)(ob + i * 32);
#pragma unroll
                for (int i = 0; i < 8; ++i)
                    acc = MFMA(__builtin_bit_cast(half8, fr[i]), wf[i], acc);
#pragma unroll
                for (int i = 0; i < 8; ++i) fr[i] = *(const u32x4*)(ob + 256 + i * 32);
#pragma unroll
                for (int i = 0; i < 8; ++i)
                    acc = MFMA(__builtin_bit_cast(half8, fr[i]), wf[8 + i], acc);
                *(floatx4*)(red + lane * 16) = acc;
            }
            __syncthreads();                         // red ready
            if (part == 0) {
                floatx4 o = *(const floatx4*)(red + lane * 16);
#pragma unroll
                for (int j = 0; j < 4; ++j) {
                    vj[j] = fast_tanh(acc[j] + o[j] + bias);
                    *(_Float16*)(ts + (q * 4 + j) * 32 + r * 2) = (_Float16)vj[j];
                }
                asm volatile("s_waitcnt lgkmcnt(0)" ::: "memory");
                u32x2 tv = *(const u32x2*)(ts + rr * 32 + cg * 8);
                agent_store8(hst, tv);               // coalesced 8B agent store
            }
            asm volatile("" ::: "memory");
            __builtin_amdgcn_s_waitcnt(0x0F70);      // vmcnt(0)
            __syncthreads();                         // drained; red/ts reuse safe
            if (tid == 0)
                __hip_atomic_store(myf, t + 1, __ATOMIC_RELAXED, __HIP_MEMORY_SCOPE_AGENT);
            if (part == 0) {                         // out1 fp32 AFTER flag
#pragma unroll
                for (int j = 0; j < 4; ++j)
                    o1[(size_t)j * kT * kH + (size_t)t * kH] = vj[j];
            }
            hb += kBH; ob += kBH; hst += kBH;
        }
    }
}

__global__ void finalize_kernel(const _Float16* __restrict__ out0m,
                                const _Float16* __restrict__ h1m,
                                float* __restrict__ out) {
    int idx = blockIdx.x * blockDim.x + threadIdx.x;  // 0 .. 65535
    float* hn = out + (size_t)kB * kT * kH;
    if (idx < kBH) hn[idx] = (float)out0m[(size_t)kT * kBH + idx];
    else hn[idx] = (float)h1m[(size_t)kT * kBH + (idx - kBH)];
}

extern "C" void kernel_launch(void* const* d_in, const int* in_sizes, int n_in,
                              void* d_out, int out_size, void* d_ws, size_t ws_size,
                              hipStream_t stream) {
    const float* x    = (const float*)d_in[0];
    const float* h0in = (const float*)d_in[1];
    const float* wih0 = (const float*)d_in[2];
    const float* whh0 = (const float*)d_in[3];
    const float* bih0 = (const float*)d_in[4];
    const float* bhh0 = (const float*)d_in[5];
    const float* wih1 = (const float*)d_in[6];
    const float* whh1 = (const float*)d_in[7];
    const float* bih1 = (const float*)d_in[8];
    const float* bhh1 = (const float*)d_in[9];
    float* out = (float*)d_out;
    char* ws = (char*)d_ws;

    _Float16* w16    = (_Float16*)(ws + W16_B);
    _Float16* wh0_16 = (_Float16*)(ws + WH0_B);
    _Float16* wi1_16 = (_Float16*)(ws + WI1_B);
    _Float16* wh1_16 = (_Float16*)(ws + WH1_B);
    _Float16* out0m  = (_Float16*)(ws + OUT0M_B);
    _Float16* h1m    = (_Float16*)(ws + H1M_B);
    int* cnt         = (int*)(ws + CNT_B);

    setup_kernel<<<2048, 256, 0, stream>>>(h0in, wih0, whh0, wih1, whh1,
                                           w16, wh0_16, wi1_16, wh1_16, out0m, h1m, cnt);
    xw_kernel<<<4096, 256, 0, stream>>>(x, w16, bih0, bhh0, out);
    scan_kernel<<<24, 1024, 0, stream>>>(out, out0m, h1m, out,
                                         wh0_16, wi1_16, wh1_16, bih1, bhh1, cnt);
    finalize_kernel<<<256, 256, 0, stream>>>(out0m, h1m, out);
}

// Round 8
// 1978.097 us; speedup vs baseline: 3.1110x; 2.3467x over previous
//
#include <hip/hip_runtime.h>

// ---------------------------------------------------------------------------
// 2-layer tanh RNN, B=64, T=512, I=256, H=512.  Round 13: REVERT to the R6
// champion (1880us scan) verbatim structure; apply only validated micro-
// deltas.  Evidence from R7-R12: cooperative one-burst tile staging (R5/R6)
// beats per-lane direct loads / phase-split restructures by >2x every time.
// Deltas vs R6 (each mechanism-clear, each correctness-validated earlier):
//   1. publish = tanh -> per-wave LDS transpose -> coalesced 8B sc1 stores
//      (was 4x scattered 2B atomic stores/thread; shorter vmcnt(0) drain).
//   2. weights pre-converted to fp16 in setup (was per-step cvt8 of fp32).
//   3. tanhf -> fast_tanh (bit-identical absmax across rounds).
//   4. flags 128B apart (no polled-line sharing).
//   5. L1 out1 fp32 stores after the flag.
// Unchanged: 24 blocks x 1024 thr; L0 = 4 groups x 2 halves, 16 waves x
// 16 cols full-K, full-tile cooperative stage (1 x 16B/thread), S+P
// barriers; L1 = 4 groups x 4 quarters, (hh|ih) wave pairs full-K,
// cooperative stage (2 x 16B/thread per part), S+R+P barriers; R5 flag
// protocol; xw = x@Wih0+biases precomputed into d_out.
// ---------------------------------------------------------------------------

#define kB 64
#define kT 512
#define kI 256
#define kH 512
#define kBH (kB * kH)   // 32768

typedef _Float16 half8 __attribute__((ext_vector_type(8)));
typedef float floatx4 __attribute__((ext_vector_type(4)));
typedef unsigned u32x2 __attribute__((ext_vector_type(2)));

#define MFMA(a, b, c) __builtin_amdgcn_mfma_f32_16x16x32_f16(a, b, c, 0, 0, 0)

// ws layout (bytes)
constexpr size_t W16_B   = 0;                      // wih0 fp16, 256 KB
constexpr size_t WH0_B   = 1u * 1024 * 1024;       // whh0 fp16, 512 KB
constexpr size_t WI1_B   = WH0_B + 512u * 1024;    // wih1 fp16, 512 KB
constexpr size_t WH1_B   = WI1_B + 512u * 1024;    // whh1 fp16, 512 KB
constexpr size_t OUT0M_B = 16u * 1024 * 1024;                     // [T+1][B][H] fp16
constexpr size_t H1M_B   = OUT0M_B + (size_t)(kT + 1) * kBH * 2;  // [T+1][B][H] fp16
constexpr size_t CNT_B   = H1M_B + (size_t)(kT + 1) * kBH * 2;    // flags (1024 ints)

__device__ inline void agent_store8(void* p, u32x2 v) {
    asm volatile("global_store_dwordx2 %0, %1, off sc1" :: "v"(p), "v"(v) : "memory");
}
__device__ inline int aload(const int* p) {
    return __hip_atomic_load(p, __ATOMIC_RELAXED, __HIP_MEMORY_SCOPE_AGENT);
}
// flags live 128B apart (index * 32 ints)
__device__ inline void wait_slot(const int* p, int target) {
    int g = 0;
    while (aload(p) < target) if (++g > 100000000) break;   // fail-wrong, not hang
    asm volatile("" ::: "memory");   // keep gated loads below the gate
}
__device__ inline void wait_pair(const int* f, int target) {
    const int* p = f + (threadIdx.x & 1) * 32;
    int g = 0;
    for (;;) { int v = aload(p); if (__all(v >= target)) break; if (++g > 100000000) break; }
    asm volatile("" ::: "memory");
}
__device__ inline void wait_quad(const int* f, int own, int target) {
    const int idx = threadIdx.x & 3;
    const int* p = f + idx * 32;
    int g = 0;
    for (;;) {
        int v = (idx == own) ? target : aload(p);
        if (__all(v >= target)) break;
        if (++g > 100000000) break;
    }
    asm volatile("" ::: "memory");
}

__device__ inline float fast_tanh(float x) {
    float e = __expf(2.f * x);
    return 1.f - 2.f / (e + 1.f);   // exact +-1 saturation, no NaN
}

__device__ inline half8 cvt8(const float* p) {
    const float4* p4 = (const float4*)p;
    float4 a = p4[0], b = p4[1];
    half8 h;
    h[0] = (_Float16)a.x; h[1] = (_Float16)a.y; h[2] = (_Float16)a.z; h[3] = (_Float16)a.w;
    h[4] = (_Float16)b.x; h[5] = (_Float16)b.y; h[6] = (_Float16)b.z; h[7] = (_Float16)b.w;
    return h;
}

// ---------------------------------------------------------------------------
__global__ void setup_kernel(const float* __restrict__ h0,
                             const float* __restrict__ wih0, const float* __restrict__ whh0,
                             const float* __restrict__ wih1, const float* __restrict__ whh1,
                             _Float16* __restrict__ w16, _Float16* __restrict__ wh0_16,
                             _Float16* __restrict__ wi1_16, _Float16* __restrict__ wh1_16,
                             _Float16* __restrict__ out0m, _Float16* __restrict__ h1m,
                             int* __restrict__ cnt) {
    size_t tid = (size_t)blockIdx.x * blockDim.x + threadIdx.x;
    size_t stride = (size_t)gridDim.x * blockDim.x;
    for (size_t i = tid; i < (size_t)kH * kI; i += stride) w16[i] = (_Float16)wih0[i];
    for (size_t i = tid; i < (size_t)kH * kH; i += stride) {
        wh0_16[i] = (_Float16)whh0[i];
        wi1_16[i] = (_Float16)wih1[i];
        wh1_16[i] = (_Float16)whh1[i];
    }
    for (size_t i = tid; i < kBH; i += stride) {
        out0m[i] = (_Float16)h0[i];          // h(0) layer0 -> slab 0
        h1m[i]   = (_Float16)h0[kBH + i];    // h(0) layer1 -> slab 0
    }
    if (tid < 1024) cnt[tid] = 0;
}

// xw[b][t][c] = sum_i x[b,t,i]*Wih0[c,i] + bih0[c] + bhh0[c]   (fp32, into d_out)
__global__ __launch_bounds__(256) void xw_kernel(
    const float* __restrict__ x, const _Float16* __restrict__ w16,
    const float* __restrict__ bih, const float* __restrict__ bhh, float* xw) {
    const int mb = blockIdx.x >> 3, nb = blockIdx.x & 7;
    const int wave = threadIdx.x >> 6, lane = threadIdx.x & 63;
    const int r = lane & 15, q = lane >> 4;
    const int m0 = mb * 64 + wave * 16;
    half8 a[8];
#pragma unroll
    for (int ko = 0; ko < 8; ++ko)
        a[ko] = cvt8(x + (size_t)(m0 + r) * kI + ko * 32 + q * 8);
#pragma unroll
    for (int ct = 0; ct < 4; ++ct) {
        const int cc = nb * 64 + ct * 16 + r;
        const float bias = bih[cc] + bhh[cc];
        floatx4 acc = {bias, bias, bias, bias};
#pragma unroll
        for (int ko = 0; ko < 8; ++ko) {
            half8 b = *(const half8*)(w16 + (size_t)cc * kI + ko * 32 + q * 8);
            acc = MFMA(a[ko], b, acc);
        }
#pragma unroll
        for (int j = 0; j < 4; ++j)
            xw[(size_t)(m0 + q * 4 + j) * kH + cc] = acc[j];
    }
}

// ---------------------------------------------------------------------------
__global__ __launch_bounds__(1024) void scan_kernel(
    const float* xw,                       // = d_out (fp32 [B][T][H]), layer0 reads
    _Float16* out0m, _Float16* h1m,
    float* out1,                           // = d_out, layer1 writes
    const _Float16* __restrict__ wh0_16,
    const _Float16* __restrict__ wi1_16, const _Float16* __restrict__ wh1_16,
    const float* __restrict__ bih1, const float* __restrict__ bhh1,
    int* cnt) {
    __shared__ __align__(16) char smem[45056];

    const int blk = blockIdx.x;
    const int tid = threadIdx.x;
    const int wave = tid >> 6, lane = tid & 63;
    const int r = lane & 15, q = lane >> 4;
    const int rb = (r << 10), swz = (r & 7) << 4;    // MFMA A-read addressing
    const int rr = lane >> 2, cg = lane & 3;         // publish-transpose roles

    if (blk < 8) {
        // ===== layer 0: 4 groups x 2 halves, 16 waves x 16 cols, full-K =====
        const int g = blk >> 1, hf = blk & 1;
        const int b0 = g * 16;
        const int cc = hf * 256 + wave * 16 + r;     // weight row / output col
        half8 wfh[16];                               // full-K fp16 weights
#pragma unroll
        for (int ks = 0; ks < 16; ++ks)
            wfh[ks] = *(const half8*)(wh0_16 + (size_t)cc * kH + ks * 32 + q * 8);
        int* myf = cnt + (g * 2 + hf) * 32;
        const int* pef = cnt + (g * 2 + (hf ^ 1)) * 32;
        // cooperative staging: one 16B unit / thread covers [16][512] fp16
        const int srow = tid >> 6, sunit = tid & 63;
        const size_t sg_off = (size_t)(b0 + srow) * kH + sunit * 8;
        char* sdst = smem + (((srow << 10) | (sunit << 4)) ^ ((srow & 7) << 4));
        char* ts = smem + 16384 + wave * 512;        // per-wave [16][16] fp16
        _Float16* st = out0m + (size_t)kBH + (size_t)(b0 + rr) * kH
                       + hf * 256 + wave * 16 + cg * 4;

        for (int t = 0; t < kT; ++t) {
            float xwv[4];                            // epilogue-only, pre-gate
#pragma unroll
            for (int j = 0; j < 4; ++j)
                xwv[j] = xw[((size_t)(b0 + q * 4 + j) * kT + t) * kH + cc];
            if (t > 0) wait_slot(pef, t);            // peer half of h(t) published
            *(half8*)sdst = *(const half8*)(out0m + (size_t)t * kBH + sg_off);
            __syncthreads();                         // S: tile staged
            floatx4 acc = {0.f, 0.f, 0.f, 0.f};
#pragma unroll
            for (int ks = 0; ks < 16; ++ks) {
                half8 la = *(const half8*)(smem + ((rb | (ks << 6) | (q << 4)) ^ swz));
                acc = MFMA(la, wfh[ks], acc);
            }
            // epilogue: tanh -> per-wave transpose -> coalesced 8B sc1 store
#pragma unroll
            for (int j = 0; j < 4; ++j) {
                float v = fast_tanh(acc[j] + xwv[j]);
                *(_Float16*)(ts + (q * 4 + j) * 32 + r * 2) = (_Float16)v;
            }
            asm volatile("s_waitcnt lgkmcnt(0)" ::: "memory");
            u32x2 tv = *(const u32x2*)(ts + rr * 32 + cg * 8);
            agent_store8(st, tv);
            // publish: drain -> barrier -> one flag store (R5 recipe)
            asm volatile("" ::: "memory");
            __builtin_amdgcn_s_waitcnt(0x0F70);      // vmcnt(0): all stores drained
            __syncthreads();                         // P (also fences stage reuse)
            if (tid == 0)
                __hip_atomic_store(myf, t + 1, __ATOMIC_RELAXED, __HIP_MEMORY_SCOPE_AGENT);
            st += kBH;
        }
    } else {
        // ===== layer 1: 4 groups x 4 quarters, 8 (hh|ih) wave pairs, full-K =====
        const int b2 = blk - 8;
        const int g = b2 >> 2, qb = b2 & 3;
        const int b0 = g * 16;
        const int ct = wave >> 1, part = wave & 1;   // pair ct, part0=hh part1=ih
        const int cc = qb * 128 + ct * 16 + r;
        half8 wf[16];                                // one matrix full-K fp16
        const _Float16* wsrc = part ? wi1_16 : wh1_16;
#pragma unroll
        for (int ks = 0; ks < 16; ++ks)
            wf[ks] = *(const half8*)(wsrc + (size_t)cc * kH + ks * 32 + q * 8);
        const float bias = (part == 0) ? (bih1[cc] + bhh1[cc]) : 0.f;
        int* myf = cnt + (8 + g * 4 + qb) * 32;
        const int* qf = cnt + (8 + g * 4) * 32;      // own-layer quarter flags
        const int* lf = cnt + (g * 2) * 32;          // layer0 half flags
        // staging: 512 threads per part, two 16B units each -> [16][512] fp16
        const int u = ct * 64 + lane;
        const int srow = u >> 5, sunit = u & 31;
        const size_t sg_off = (size_t)(b0 + srow) * kH + sunit * 16;
        const int tbase = part ? 16384 : 0;
        char* sd0 = smem + tbase + (((srow << 10) | (sunit << 5)) ^ ((srow & 7) << 4));
        char* sd1 = smem + tbase + ((((srow << 10) | (sunit << 5)) | 16) ^ ((srow & 7) << 4));
        float* redp = (float*)(smem + 32768) + (ct * 256 + lane * 4);
        char* tsp = smem + 40960 + ct * 512;         // per-pair [16][16] fp16 (part0)
        _Float16* hst = h1m + (size_t)kBH + (size_t)(b0 + rr) * kH
                        + qb * 128 + ct * 16 + cg * 4;
        float* o1 = out1 + (size_t)(b0 + q * 4) * kT * kH + cc;

        for (int t = 0; t < kT; ++t) {
            const _Float16* sl;
            if (part == 0) {                         // own h1(t) tile
                if (t > 0) wait_quad(qf, qb, t);
                sl = h1m + (size_t)t * kBH;
            } else {                                 // layer0 output for step t
                wait_pair(lf, t + 1);
                sl = out0m + (size_t)(t + 1) * kBH;
            }
            half8 s0 = *(const half8*)(sl + sg_off);
            half8 s1 = *(const half8*)(sl + sg_off + 8);
            *(half8*)sd0 = s0;
            *(half8*)sd1 = s1;
            __syncthreads();                         // S: both tiles staged
            floatx4 acc = {0.f, 0.f, 0.f, 0.f};
            const char* tb = smem + tbase;
#pragma unroll
            for (int ks = 0; ks < 16; ++ks) {
                half8 la = *(const half8*)(tb + ((rb | (ks << 6) | (q << 4)) ^ swz));
                acc = MFMA(la, wf[ks], acc);
            }
            if (part == 1) *(floatx4*)redp = acc;
            __syncthreads();                         // R: partials ready
            float vj[4];
            if (part == 0) {
                floatx4 o = *(const floatx4*)redp;
#pragma unroll
                for (int j = 0; j < 4; ++j) {
                    vj[j] = fast_tanh(acc[j] + o[j] + bias);
                    *(_Float16*)(tsp + (q * 4 + j) * 32 + r * 2) = (_Float16)vj[j];
                }
                asm volatile("s_waitcnt lgkmcnt(0)" ::: "memory");
                u32x2 tv = *(const u32x2*)(tsp + rr * 32 + cg * 8);
                agent_store8(hst, tv);               // coalesced 8B agent store
            }
            asm volatile("" ::: "memory");
            __builtin_amdgcn_s_waitcnt(0x0F70);      // vmcnt(0)
            __syncthreads();                         // P: drained + LDS reuse safe
            if (tid == 0)
                __hip_atomic_store(myf, t + 1, __ATOMIC_RELAXED, __HIP_MEMORY_SCOPE_AGENT);
            if (part == 0) {                         // out1 fp32 AFTER the flag
#pragma unroll
                for (int j = 0; j < 4; ++j)
                    o1[(size_t)j * kT * kH + (size_t)t * kH] = vj[j];
            }
            hst += kBH;
        }
    }
}

__global__ void finalize_kernel(const _Float16* __restrict__ out0m,
                                const _Float16* __restrict__ h1m,
                                float* __restrict__ out) {
    int idx = blockIdx.x * blockDim.x + threadIdx.x;  // 0 .. 65535
    float* hn = out + (size_t)kB * kT * kH;
    if (idx < kBH) hn[idx] = (float)out0m[(size_t)kT * kBH + idx];
    else hn[idx] = (float)h1m[(size_t)kT * kBH + (idx - kBH)];
}

extern "C" void kernel_launch(void* const* d_in, const int* in_sizes, int n_in,
                              void* d_out, int out_size, void* d_ws, size_t ws_size,
                              hipStream_t stream) {
    const float* x    = (const float*)d_in[0];
    const float* h0in = (const float*)d_in[1];
    const float* wih0 = (const float*)d_in[2];
    const float* whh0 = (const float*)d_in[3];
    const float* bih0 = (const float*)d_in[4];
    const float* bhh0 = (const float*)d_in[5];
    const float* wih1 = (const float*)d_in[6];
    const float* whh1 = (const float*)d_in[7];
    const float* bih1 = (const float*)d_in[8];
    const float* bhh1 = (const float*)d_in[9];
    float* out = (float*)d_out;
    char* ws = (char*)d_ws;

    _Float16* w16    = (_Float16*)(ws + W16_B);
    _Float16* wh0_16 = (_Float16*)(ws + WH0_B);
    _Float16* wi1_16 = (_Float16*)(ws + WI1_B);
    _Float16* wh1_16 = (_Float16*)(ws + WH1_B);
    _Float16* out0m  = (_Float16*)(ws + OUT0M_B);
    _Float16* h1m    = (_Float16*)(ws + H1M_B);
    int* cnt         = (int*)(ws + CNT_B);

    setup_kernel<<<2048, 256, 0, stream>>>(h0in, wih0, whh0, wih1, whh1,
                                           w16, wh0_16, wi1_16, wh1_16, out0m, h1m, cnt);
    xw_kernel<<<4096, 256, 0, stream>>>(x, w16, bih0, bhh0, out);
    scan_kernel<<<24, 1024, 0, stream>>>(out, out0m, h1m, out,
                                         wh0_16, wi1_16, wh1_16, bih1, bhh1, cnt);
    finalize_kernel<<<256, 256, 0, stream>>>(out0m, h1m, out);
}